// Round 4
// baseline (576.808 us; speedup 1.0000x reference)
//
#include <hip/hip_runtime.h>
#include <math.h>

#define B_ 4
#define NTOK 1537
#define NH 16
#define NROWS 6148      // B_*NTOK
#define RPAD 6272       // 49*128, padded rows
#define KDIM 1024
#define NKPAD 1568      // keys padded to 32-mult for aligned V^T loads

typedef __attribute__((ext_vector_type(8))) short short8;
typedef __attribute__((ext_vector_type(4))) float f32x4;
typedef __attribute__((ext_vector_type(4))) unsigned short ushort4v;
typedef __attribute__((ext_vector_type(4))) unsigned int uint4v;
typedef __attribute__((ext_vector_type(2))) unsigned int uint2v;

__device__ __forceinline__ float bf2f(unsigned short u){
  unsigned int x = ((unsigned int)u) << 16;
  return __uint_as_float(x);
}
__device__ __forceinline__ unsigned short f2bf(float f){
  unsigned int x = __float_as_uint(f);
  x += 0x7fff + ((x >> 16) & 1);   // RNE
  return (unsigned short)(x >> 16);
}
__device__ __forceinline__ unsigned int pack_bf16(float lo, float hi){
  return (unsigned int)f2bf(lo) | ((unsigned int)f2bf(hi) << 16);
}
__device__ __forceinline__ void gload_lds16(const void* g, void* l){
  __builtin_amdgcn_global_load_lds((const __attribute__((address_space(1))) unsigned int*)g,
                                   (__attribute__((address_space(3))) unsigned int*)l, 16, 0, 0);
}
__device__ __forceinline__ f32x4 mfma16(short8 a, short8 b, f32x4 c){
  return __builtin_amdgcn_mfma_f32_16x16x32_bf16(a, b, c, 0, 0, 0);
}

// ---------------- conversions ----------------
__global__ __launch_bounds__(256) void cvt_w_kernel(const float* __restrict__ src,
                                                    unsigned short* __restrict__ dst, int n){
  int i = (blockIdx.x*256 + threadIdx.x)*4;
  if (i >= n) return;
  f32x4 v = *(const f32x4*)(src + i);
  ushort4v o;
  #pragma unroll
  for (int j=0;j<4;j++) o[j] = f2bf(v[j]);
  *(ushort4v*)(dst + i) = o;
}

__global__ __launch_bounds__(256) void cvt_x_kernel(const float* __restrict__ x,
                                                    unsigned short* __restrict__ xb){
  size_t i = ((size_t)blockIdx.x*256 + threadIdx.x)*4;
  if (i >= (size_t)RPAD*KDIM) return;
  size_t row = i >> 10;
  ushort4v o;
  if (row < NROWS){
    f32x4 v = *(const f32x4*)(x + i);
    #pragma unroll
    for (int j=0;j<4;j++) o[j] = f2bf(v[j]);
  } else {
    o = (ushort4v)0;
  }
  *(ushort4v*)(xb + i) = o;
}

// ---------------- RoPE tables (pos 0..12, 32 freqs) ----------------
__global__ void rope_tables_kernel(float* __restrict__ ct, float* __restrict__ st){
  int i = threadIdx.x;
  if (i >= 13*32) return;
  int p = i >> 5, j = i & 31;
  float th = powf(10000.f, -(float)j * (1.f/32.f));
  float ang = (float)p * th;
  ct[i] = cosf(ang);
  st[i] = sinf(ang);
}

// ---------------- stable argsort -> pos table ----------------
// grid (B_, 6): each block ranks 256 elements of one batch.
__global__ __launch_bounds__(256) void argsort_kernel(const int* __restrict__ ids,
                                                      int* __restrict__ postab){
  __shared__ int vals[1536];
  int b = blockIdx.x;
  const int* src = ids + b*1536;
  for (int i=threadIdx.x; i<1536; i+=256) vals[i] = src[i];
  __syncthreads();
  int i = blockIdx.y*256 + threadIdx.x;
  int v = vals[i];
  int rank = 0;
  for (int j=0;j<1536;j++){
    int u = vals[j];
    rank += (u < v) || (u == v && j < i);   // stable rank
  }
  postab[b*1536 + rank] = (i % 12) + 1;     // (p % V) + 1
}

// ---------------- RoPE apply, in-place on bf16 qkv (q and k parts) ----------------
__global__ __launch_bounds__(256) void rope_kernel(unsigned short* __restrict__ qkv,
                                                   const int* __restrict__ postab,
                                                   const float* __restrict__ ct,
                                                   const float* __restrict__ st){
  int idx = blockIdx.x*256 + threadIdx.x;
  if (idx >= B_*NTOK*NH) return;
  int h = idx & 15;
  int bn = idx >> 4;
  int b = bn / NTOK;
  int n = bn - b*NTOK;
  unsigned short* rowp = qkv + (size_t)bn*3072;
  int pos = (n == 0) ? 0 : postab[b*1536 + (n-1)];
  const float* cr = ct + pos*32;
  const float* sr = st + pos*32;
  #pragma unroll
  for (int part=0; part<2; part++){
    unsigned short* p = rowp + part*1024 + h*64;
    uint4v vv[8];
    #pragma unroll
    for (int i=0;i<8;i++) vv[i] = ((const uint4v*)p)[i];
    unsigned short* tp = (unsigned short*)vv;
    unsigned short ov[64];
    if (n == 0){
      #pragma unroll
      for (int j=0;j<32;j++){ ov[j] = tp[2*j]; ov[32+j] = tp[2*j+1]; }
    } else {
      #pragma unroll
      for (int j=0;j<32;j++){
        float re = bf2f(tp[2*j]), im = bf2f(tp[2*j+1]);
        float c = cr[j], s = sr[j];
        ov[j]    = f2bf(re*c - im*s);
        ov[32+j] = f2bf(re*s + im*c);
      }
    }
    #pragma unroll
    for (int i=0;i<8;i++) ((uint4v*)p)[i] = ((const uint4v*)ov)[i];
  }
}

// ---------------- bf16 MFMA GEMM body: out[r][c] = (sum_k A[r][k]*W[c][k] + bias[c]) * scale
__device__ __forceinline__ void gemm_body(const unsigned short* __restrict__ A, int lda,
    const unsigned short* __restrict__ W,
    const float* __restrict__ bias, float scale,
    unsigned short* __restrict__ outb, float* __restrict__ outf, int ldo, int mvalid,
    int rowBase, int colBase)
{
  __shared__ alignas(16) unsigned short At[128][32];
  __shared__ alignas(16) unsigned short Bt[128][32];
  int t = threadIdx.x, w = t >> 6, lane = t & 63;
  int g = lane >> 4, l15 = lane & 15;
  int rb = (w >> 1) * 64, cb = (w & 1) * 64;
  f32x4 acc[4][4];
  #pragma unroll
  for (int m=0;m<4;m++)
    #pragma unroll
    for (int n=0;n<4;n++) acc[m][n] = 0.f;
  int srow = lane >> 2;            // 0..15
  int scol = (lane & 3) * 8;       // 0,8,16,24
  for (int kb = 0; kb < KDIM; kb += 32){
    __syncthreads();
    #pragma unroll
    for (int i=0;i<2;i++){
      int rr = i*64 + w*16 + srow;
      gload_lds16(A + (size_t)(rowBase + rr)*lda + kb + scol, &At[i*64 + w*16][0]);
      gload_lds16(W + (size_t)(colBase + rr)*KDIM + kb + scol, &Bt[i*64 + w*16][0]);
    }
    __syncthreads();
    short8 af[4], bf[4];
    #pragma unroll
    for (int m=0;m<4;m++) af[m] = *(const short8*)&At[rb + m*16 + l15][g*8];
    #pragma unroll
    for (int n=0;n<4;n++) bf[n] = *(const short8*)&Bt[cb + n*16 + l15][g*8];
    #pragma unroll
    for (int m=0;m<4;m++)
      #pragma unroll
      for (int n=0;n<4;n++)
        acc[m][n] = mfma16(af[m], bf[n], acc[m][n]);
  }
  #pragma unroll
  for (int m=0;m<4;m++)
    #pragma unroll
    for (int n=0;n<4;n++){
      int col = colBase + cb + n*16 + l15;
      float bv = bias ? bias[col] : 0.f;
      #pragma unroll
      for (int r=0;r<4;r++){
        int row = rowBase + rb + m*16 + g*4 + r;
        if (row < mvalid){
          float v = (acc[m][n][r] + bv) * scale;
          if (outf) outf[(size_t)row*ldo + col] = v;
          else      outb[(size_t)row*ldo + col] = f2bf(v);
        }
      }
    }
}

__global__ __launch_bounds__(256) void gemm_kernel(const unsigned short* __restrict__ A, int lda,
    const unsigned short* __restrict__ W,
    const float* __restrict__ bias, float scale,
    unsigned short* __restrict__ outb, float* __restrict__ outf, int ldo, int mvalid)
{
  gemm_body(A, lda, W, bias, scale, outb, outf, ldo, mvalid,
            blockIdx.x*128, blockIdx.y*128);
}

// merged in_proj: z = 0,1,2 -> q,k,v
__global__ __launch_bounds__(256) void gemm_inproj_kernel(const unsigned short* __restrict__ qkvb,
    const unsigned short* __restrict__ ipwb, const float* __restrict__ ipb,
    unsigned short* __restrict__ qpb, unsigned short* __restrict__ kpb,
    unsigned short* __restrict__ vpb)
{
  int z = blockIdx.z;
  const unsigned short* A = qkvb + z*1024;
  const unsigned short* W = ipwb + (size_t)z*1024*1024;
  const float* bias = ipb + z*1024;
  float scale = (z == 0) ? 0.125f : 1.f;
  unsigned short* outb = (z == 0) ? qpb : (z == 1 ? kpb : vpb);
  gemm_body(A, 3072, W, bias, scale, outb, nullptr, 1024, NROWS,
            blockIdx.x*128, blockIdx.y*128);
}

// ---------------- V transpose: vp[b*NTOK+n][h*64+e] -> vt[((b*16+h)*64+e)][NKPAD keys]
__global__ __launch_bounds__(256) void vtrans_kernel(const unsigned short* __restrict__ vp,
                                                     unsigned short* __restrict__ vt){
  __shared__ alignas(16) unsigned short Tl[64][72];
  int tile = blockIdx.x, head = blockIdx.y, b = blockIdx.z;
  int t = threadIdx.x;
  {
    int r = t >> 2, ch = t & 3;
    int tok = tile*64 + r;
    uint4v v0, v1;
    if (tok < NTOK){
      const unsigned short* src = vp + (size_t)(b*NTOK + tok)*KDIM + head*64 + ch*16;
      v0 = *(const uint4v*)src;
      v1 = *(const uint4v*)(src + 8);
    } else { v0 = (uint4v)0; v1 = (uint4v)0; }
    *(uint4v*)&Tl[r][ch*16]     = v0;
    *(uint4v*)&Tl[r][ch*16 + 8] = v1;
  }
  __syncthreads();
  {
    int c = t & 63, rchunk = t >> 6;
    int tokBase = tile*64 + rchunk*16;
    if (tokBase < NKPAD){
      unsigned short ov[16];
      #pragma unroll
      for (int j=0;j<16;j++) ov[j] = Tl[rchunk*16 + j][c];
      unsigned short* dst = vt + ((size_t)(((b*16 + head) << 6) + c))*NKPAD + tokBase;
      *(uint4v*)dst       = *(const uint4v*)&ov[0];
      *(uint4v*)(dst + 8) = *(const uint4v*)&ov[8];
    }
  }
}

// ---------------- flash attention, swapped-operand (P col = q = l15, lane-local softmax)
// grid (B*H, ceil(N/64)); 4 independent waves, each owns 16 q rows.
__global__ __launch_bounds__(256) void attn_kernel(const unsigned short* __restrict__ qp,
    const unsigned short* __restrict__ kp, const unsigned short* __restrict__ vt,
    unsigned short* __restrict__ ctx)
{
  __shared__ alignas(16) unsigned short Plds[4][16][40];   // [wave][q=16][32 keys + 8 pad]
  int bh = blockIdx.x;
  int qt = blockIdx.y;
  int b = bh >> 4, h = bh & 15;
  int t = threadIdx.x, w = t >> 6, lane = t & 63;
  int g = lane >> 4, l15 = lane & 15;
  int qrow = qt*64 + w*16 + l15;
  int qcl = qrow > NTOK-1 ? NTOK-1 : qrow;
  const unsigned short* qb = qp + (((size_t)(b*NTOK + qcl)*NH + h) << 6);
  short8 qf[2];
  qf[0] = *(const short8*)(qb + g*8);
  qf[1] = *(const short8*)(qb + 32 + g*8);
  // K: A-operand rows = keys; lane loads key kt*32 + l15 (+16 for c1), e-chunk g*8 (+32)
  const unsigned short* kptr = kp + (((size_t)(b*NTOK + l15)*NH + h) << 6) + g*8;
  // V^T: A rows = d; lane row bh*64 + dblk*16 + l15, key col kt*32 + g*8
  const unsigned short* vptr = vt + ((size_t)((bh << 6) + l15))*NKPAD + g*8;
  unsigned short (*pl)[40] = Plds[w];
  float m_ = -3e38f, l_ = 0.f;
  f32x4 o_[4];
  #pragma unroll
  for (int d=0;d<4;d++) o_[d] = 0.f;

  auto soft_pv = [&](int kt, f32x4 c0, f32x4 c1){
    // row max over 32 keys: 8 in-lane + across the 4 g-lanes
    float mx = fmaxf(fmaxf(fmaxf(c0[0],c0[1]), fmaxf(c0[2],c0[3])),
                     fmaxf(fmaxf(c1[0],c1[1]), fmaxf(c1[2],c1[3])));
    mx = fmaxf(mx, __shfl_xor(mx, 16));
    mx = fmaxf(mx, __shfl_xor(mx, 32));
    float mn = fmaxf(m_, mx);
    float al = __expf(m_ - mn);
    m_ = mn;
    float p0[4], p1[4];
    float rs = 0.f;
    #pragma unroll
    for (int r=0;r<4;r++){
      p0[r] = __expf(c0[r] - mn);
      p1[r] = __expf(c1[r] - mn);
      rs += p0[r] + p1[r];
    }
    rs += __shfl_xor(rs, 16);
    rs += __shfl_xor(rs, 32);
    l_ = l_*al + rs;
    #pragma unroll
    for (int d=0;d<4;d++)
      #pragma unroll
      for (int r=0;r<4;r++) o_[d][r] *= al;
    // stage P: lane (g,l15) owns P[q=l15][keys g*4+0..3] and [16+g*4+0..3]
    uint2v w0, w1;
    w0[0] = pack_bf16(p0[0], p0[1]); w0[1] = pack_bf16(p0[2], p0[3]);
    w1[0] = pack_bf16(p1[0], p1[1]); w1[1] = pack_bf16(p1[2], p1[3]);
    *(uint2v*)&pl[l15][g*4]      = w0;
    *(uint2v*)&pl[l15][16 + g*4] = w1;
    asm volatile("s_waitcnt lgkmcnt(0)" ::: "memory");   // wave-local LDS ordering
    __builtin_amdgcn_sched_barrier(0);                   // rule #18: pin reads after waitcnt
    short8 pf = *(const short8*)&pl[l15][g*8];           // B-operand: P[q=l15][keys g*8..+8]
    const unsigned short* vb = vptr + kt*32;
    #pragma unroll
    for (int d=0;d<4;d++){
      short8 vf = *(const short8*)(vb + (size_t)(d*16)*NKPAD);
      o_[d] = mfma16(vf, pf, o_[d]);                     // D: row=d(g*4+r), col=q=l15
    }
  };

  for (int kt=0; kt<48; ++kt){
    short8 a00 = *(const short8*)(kptr);
    short8 a01 = *(const short8*)(kptr + 32);
    short8 a10 = *(const short8*)(kptr + 16*1024);
    short8 a11 = *(const short8*)(kptr + 16*1024 + 32);
    kptr += 32*1024;
    f32x4 c0 = 0.f, c1 = 0.f;
    c0 = mfma16(a00, qf[0], c0);
    c1 = mfma16(a10, qf[0], c1);
    c0 = mfma16(a01, qf[1], c0);
    c1 = mfma16(a11, qf[1], c1);
    soft_pv(kt, c0, c1);
  }
  // tail: keys 1536..1567, only 1536 valid
  {
    const unsigned short* k0 = kp + (((size_t)(b*NTOK + (NTOK-1))*NH + h) << 6) + g*8;
    short8 a00 = *(const short8*)(k0);
    short8 a01 = *(const short8*)(k0 + 32);
    f32x4 c0 = 0.f;
    c0 = mfma16(a00, qf[0], c0);
    c0 = mfma16(a01, qf[1], c0);
    f32x4 c1;
    #pragma unroll
    for (int r=0;r<4;r++){
      if (g*4 + r >= 1) c0[r] = -1e30f;
      c1[r] = -1e30f;
    }
    soft_pv(48, c0, c1);
  }
  // write: o_[dblk][r] = ctx[q=l15][d = dblk*16 + g*4 + r]
  int n = qt*64 + w*16 + l15;
  if (n < NTOK){
    float inv = 1.f / l_;
    unsigned short* cb = ctx + (((size_t)(b*NTOK + n)*NH + h) << 6) + g*4;
    #pragma unroll
    for (int d=0;d<4;d++){
      uint2v uu;
      uu[0] = pack_bf16(o_[d][0]*inv, o_[d][1]*inv);
      uu[1] = pack_bf16(o_[d][2]*inv, o_[d][3]*inv);
      *(uint2v*)(cb + d*16) = uu;
    }
  }
}

extern "C" void kernel_launch(void* const* d_in, const int* in_sizes, int n_in,
                              void* d_out, int out_size, void* d_ws, size_t ws_size,
                              hipStream_t stream)
{
  const float* x    = (const float*)d_in[0];
  const float* qkvw = (const float*)d_in[1];
  const float* ipw  = (const float*)d_in[2];
  const float* ipb  = (const float*)d_in[3];
  const float* opw  = (const float*)d_in[4];
  const float* opb  = (const float*)d_in[5];
  const float* pw   = (const float*)d_in[6];
  const float* pb   = (const float*)d_in[7];
  const int*   ids  = (const int*)d_in[8];
  float* out = (float*)d_out;

  char* p = (char*)d_ws;
  auto alloc = [&](size_t bytes)->char* {
    char* r = p; p += (bytes + 255) & ~(size_t)255; return r;
  };
  unsigned short* xb    = (unsigned short*)alloc((size_t)RPAD*1024*2);   // reused as vt
  unsigned short* qkvwb = (unsigned short*)alloc((size_t)3072*1024*2);
  unsigned short* ipwb  = (unsigned short*)alloc((size_t)3072*1024*2);
  unsigned short* opwb  = (unsigned short*)alloc((size_t)1024*1024*2);
  unsigned short* pwb   = (unsigned short*)alloc((size_t)1024*1024*2);
  unsigned short* qkvb  = (unsigned short*)alloc((size_t)RPAD*3072*2);
  unsigned short* qpb   = (unsigned short*)alloc((size_t)RPAD*1024*2);
  unsigned short* kpb   = (unsigned short*)alloc((size_t)RPAD*1024*2);
  unsigned short* vpb   = (unsigned short*)alloc((size_t)RPAD*1024*2);
  unsigned short* ctxb  = (unsigned short*)alloc((size_t)RPAD*1024*2);
  unsigned short* mhab  = (unsigned short*)alloc((size_t)RPAD*1024*2);
  int*   postab = (int*)alloc((size_t)B_*1536*4);
  float* ctab   = (float*)alloc(13*32*4);
  float* stab   = (float*)alloc(13*32*4);
  unsigned short* vtb = xb;   // alias: xb (12,845,056 B) == vt (4096*NKPAD*2)

  cvt_w_kernel<<<3072, 256, 0, stream>>>(qkvw, qkvwb, 3072*1024);
  cvt_w_kernel<<<3072, 256, 0, stream>>>(ipw,  ipwb,  3072*1024);
  cvt_w_kernel<<<1024, 256, 0, stream>>>(opw,  opwb,  1024*1024);
  cvt_w_kernel<<<1024, 256, 0, stream>>>(pw,   pwb,   1024*1024);
  cvt_x_kernel<<<RPAD, 256, 0, stream>>>(x, xb);
  rope_tables_kernel<<<1, 512, 0, stream>>>(ctab, stab);
  argsort_kernel<<<dim3(B_, 6), 256, 0, stream>>>(ids, postab);

  // qkv = x @ qkv_w^T  (no bias), bf16 out
  gemm_kernel<<<dim3(RPAD/128, 3072/128), 256, 0, stream>>>(xb, 1024, qkvwb, nullptr, 1.f,
                                                            qkvb, nullptr, 3072, NROWS);
  // RoPE in place on q,k
  rope_kernel<<<(B_*NTOK*NH + 255)/256, 256, 0, stream>>>(qkvb, postab, ctab, stab);
  // in_proj merged: qp (*0.125 folded), kp, vp
  gemm_inproj_kernel<<<dim3(RPAD/128, 8, 3), 256, 0, stream>>>(qkvb, ipwb, ipb, qpb, kpb, vpb);
  // V transpose into vt (aliases dead xb)
  vtrans_kernel<<<dim3(25, 16, 4), 256, 0, stream>>>(vpb, vtb);
  // attention
  attn_kernel<<<dim3(B_*NH, (NTOK+63)/64), 256, 0, stream>>>(qpb, kpb, vtb, ctxb);
  // out_proj then proj (final f32 to d_out)
  gemm_kernel<<<dim3(RPAD/128, 8), 256, 0, stream>>>(ctxb, 1024, opwb, opb, 1.f,
                                                     mhab, nullptr, 1024, NROWS);
  gemm_kernel<<<dim3(RPAD/128, 8), 256, 0, stream>>>(mhab, 1024, pwb,  pb,  1.f,
                                                     nullptr, out, 1024, NROWS);
}

// Round 5
// 548.189 us; speedup vs baseline: 1.0522x; 1.0522x over previous
//
#include <hip/hip_runtime.h>
#include <math.h>

#define B_ 4
#define NTOK 1537
#define NH 16
#define NROWS 6148      // B_*NTOK
#define RPAD 6272       // 49*128, padded rows
#define KDIM 1024
#define NKPAD 1568      // keys padded to 32-mult for aligned V^T loads

typedef __attribute__((ext_vector_type(8))) short short8;
typedef __attribute__((ext_vector_type(4))) float f32x4;
typedef __attribute__((ext_vector_type(4))) unsigned short ushort4v;
typedef __attribute__((ext_vector_type(4))) unsigned int uint4v;
typedef __attribute__((ext_vector_type(2))) unsigned int uint2v;

__device__ __forceinline__ float bf2f(unsigned short u){
  unsigned int x = ((unsigned int)u) << 16;
  return __uint_as_float(x);
}
__device__ __forceinline__ unsigned short f2bf(float f){
  unsigned int x = __float_as_uint(f);
  x += 0x7fff + ((x >> 16) & 1);   // RNE
  return (unsigned short)(x >> 16);
}
__device__ __forceinline__ unsigned int pack_bf16(float lo, float hi){
  return (unsigned int)f2bf(lo) | ((unsigned int)f2bf(hi) << 16);
}
__device__ __forceinline__ void gload_lds16(const void* g, void* l){
  __builtin_amdgcn_global_load_lds((const __attribute__((address_space(1))) unsigned int*)g,
                                   (__attribute__((address_space(3))) unsigned int*)l, 16, 0, 0);
}
__device__ __forceinline__ f32x4 mfma16(short8 a, short8 b, f32x4 c){
  return __builtin_amdgcn_mfma_f32_16x16x32_bf16(a, b, c, 0, 0, 0);
}

// ---------------- conversions ----------------
__global__ __launch_bounds__(256) void cvt_w_kernel(const float* __restrict__ src,
                                                    unsigned short* __restrict__ dst, int n){
  int i = (blockIdx.x*256 + threadIdx.x)*4;
  if (i >= n) return;
  f32x4 v = *(const f32x4*)(src + i);
  ushort4v o;
  #pragma unroll
  for (int j=0;j<4;j++) o[j] = f2bf(v[j]);
  *(ushort4v*)(dst + i) = o;
}

__global__ __launch_bounds__(256) void cvt_x_kernel(const float* __restrict__ x,
                                                    unsigned short* __restrict__ xb){
  size_t i = ((size_t)blockIdx.x*256 + threadIdx.x)*4;
  if (i >= (size_t)RPAD*KDIM) return;
  size_t row = i >> 10;
  ushort4v o;
  if (row < NROWS){
    f32x4 v = *(const f32x4*)(x + i);
    #pragma unroll
    for (int j=0;j<4;j++) o[j] = f2bf(v[j]);
  } else {
    o = (ushort4v)0;
  }
  *(ushort4v*)(xb + i) = o;
}

// ---------------- RoPE tables (pos 0..12, 32 freqs) ----------------
__global__ void rope_tables_kernel(float* __restrict__ ct, float* __restrict__ st){
  int i = threadIdx.x;
  if (i >= 13*32) return;
  int p = i >> 5, j = i & 31;
  float th = powf(10000.f, -(float)j * (1.f/32.f));
  float ang = (float)p * th;
  ct[i] = cosf(ang);
  st[i] = sinf(ang);
}

// ---------------- stable argsort -> pos table ----------------
// grid (B_, 6): each block ranks 256 elements of one batch.
__global__ __launch_bounds__(256) void argsort_kernel(const int* __restrict__ ids,
                                                      int* __restrict__ postab){
  __shared__ int vals[1536];
  int b = blockIdx.x;
  const int* src = ids + b*1536;
  for (int i=threadIdx.x; i<1536; i+=256) vals[i] = src[i];
  __syncthreads();
  int i = blockIdx.y*256 + threadIdx.x;
  int v = vals[i];
  int rank = 0;
  for (int j=0;j<1536;j++){
    int u = vals[j];
    rank += (u < v) || (u == v && j < i);   // stable rank
  }
  postab[b*1536 + rank] = (i % 12) + 1;     // (p % V) + 1
}

// ---------------- RoPE apply, in-place on bf16 qkv (q and k parts) ----------------
__global__ __launch_bounds__(256) void rope_kernel(unsigned short* __restrict__ qkv,
                                                   const int* __restrict__ postab,
                                                   const float* __restrict__ ct,
                                                   const float* __restrict__ st){
  int idx = blockIdx.x*256 + threadIdx.x;
  if (idx >= B_*NTOK*NH) return;
  int h = idx & 15;
  int bn = idx >> 4;
  int b = bn / NTOK;
  int n = bn - b*NTOK;
  unsigned short* rowp = qkv + (size_t)bn*3072;
  int pos = (n == 0) ? 0 : postab[b*1536 + (n-1)];
  const float* cr = ct + pos*32;
  const float* sr = st + pos*32;
  #pragma unroll
  for (int part=0; part<2; part++){
    unsigned short* p = rowp + part*1024 + h*64;
    uint4v vv[8];
    #pragma unroll
    for (int i=0;i<8;i++) vv[i] = ((const uint4v*)p)[i];
    unsigned short* tp = (unsigned short*)vv;
    unsigned short ov[64];
    if (n == 0){
      #pragma unroll
      for (int j=0;j<32;j++){ ov[j] = tp[2*j]; ov[32+j] = tp[2*j+1]; }
    } else {
      #pragma unroll
      for (int j=0;j<32;j++){
        float re = bf2f(tp[2*j]), im = bf2f(tp[2*j+1]);
        float c = cr[j], s = sr[j];
        ov[j]    = f2bf(re*c - im*s);
        ov[32+j] = f2bf(re*s + im*c);
      }
    }
    #pragma unroll
    for (int i=0;i<8;i++) ((uint4v*)p)[i] = ((const uint4v*)ov)[i];
  }
}

// ---------------- bf16 MFMA GEMM body: out[r][c] = (sum_k A[r][k]*W[c][k] + bias[c]) * scale
__device__ __forceinline__ void gemm_body(const unsigned short* __restrict__ A, int lda,
    const unsigned short* __restrict__ W,
    const float* __restrict__ bias, float scale,
    unsigned short* __restrict__ outb, float* __restrict__ outf, int ldo, int mvalid,
    int rowBase, int colBase)
{
  __shared__ alignas(16) unsigned short At[128][32];
  __shared__ alignas(16) unsigned short Bt[128][32];
  int t = threadIdx.x, w = t >> 6, lane = t & 63;
  int g = lane >> 4, l15 = lane & 15;
  int rb = (w >> 1) * 64, cb = (w & 1) * 64;
  f32x4 acc[4][4];
  #pragma unroll
  for (int m=0;m<4;m++)
    #pragma unroll
    for (int n=0;n<4;n++) acc[m][n] = 0.f;
  int srow = lane >> 2;            // 0..15
  int scol = (lane & 3) * 8;       // 0,8,16,24
  for (int kb = 0; kb < KDIM; kb += 32){
    __syncthreads();
    #pragma unroll
    for (int i=0;i<2;i++){
      int rr = i*64 + w*16 + srow;
      gload_lds16(A + (size_t)(rowBase + rr)*lda + kb + scol, &At[i*64 + w*16][0]);
      gload_lds16(W + (size_t)(colBase + rr)*KDIM + kb + scol, &Bt[i*64 + w*16][0]);
    }
    __syncthreads();
    short8 af[4], bf[4];
    #pragma unroll
    for (int m=0;m<4;m++) af[m] = *(const short8*)&At[rb + m*16 + l15][g*8];
    #pragma unroll
    for (int n=0;n<4;n++) bf[n] = *(const short8*)&Bt[cb + n*16 + l15][g*8];
    #pragma unroll
    for (int m=0;m<4;m++)
      #pragma unroll
      for (int n=0;n<4;n++)
        acc[m][n] = mfma16(af[m], bf[n], acc[m][n]);
  }
  #pragma unroll
  for (int m=0;m<4;m++)
    #pragma unroll
    for (int n=0;n<4;n++){
      int col = colBase + cb + n*16 + l15;
      float bv = bias ? bias[col] : 0.f;
      #pragma unroll
      for (int r=0;r<4;r++){
        int row = rowBase + rb + m*16 + g*4 + r;
        if (row < mvalid){
          float v = (acc[m][n][r] + bv) * scale;
          if (outf) outf[(size_t)row*ldo + col] = v;
          else      outb[(size_t)row*ldo + col] = f2bf(v);
        }
      }
    }
}

__global__ __launch_bounds__(256) void gemm_kernel(const unsigned short* __restrict__ A, int lda,
    const unsigned short* __restrict__ W,
    const float* __restrict__ bias, float scale,
    unsigned short* __restrict__ outb, float* __restrict__ outf, int ldo, int mvalid)
{
  gemm_body(A, lda, W, bias, scale, outb, outf, ldo, mvalid,
            blockIdx.x*128, blockIdx.y*128);
}

// merged in_proj: z = 0,1,2 -> q,k,v
__global__ __launch_bounds__(256) void gemm_inproj_kernel(const unsigned short* __restrict__ qkvb,
    const unsigned short* __restrict__ ipwb, const float* __restrict__ ipb,
    unsigned short* __restrict__ qpb, unsigned short* __restrict__ kpb,
    unsigned short* __restrict__ vpb)
{
  int z = blockIdx.z;
  const unsigned short* A = qkvb + z*1024;
  const unsigned short* W = ipwb + (size_t)z*1024*1024;
  const float* bias = ipb + z*1024;
  float scale = (z == 0) ? 0.125f : 1.f;
  unsigned short* outb = (z == 0) ? qpb : (z == 1 ? kpb : vpb);
  gemm_body(A, 3072, W, bias, scale, outb, nullptr, 1024, NROWS,
            blockIdx.x*128, blockIdx.y*128);
}

// ---------------- V transpose: vp[b*NTOK+n][h*64+e] -> vt[((b*16+h)*64+e)][NKPAD keys]
__global__ __launch_bounds__(256) void vtrans_kernel(const unsigned short* __restrict__ vp,
                                                     unsigned short* __restrict__ vt){
  __shared__ alignas(16) unsigned short Tl[64][72];
  int tile = blockIdx.x, head = blockIdx.y, b = blockIdx.z;
  int t = threadIdx.x;
  {
    int r = t >> 2, ch = t & 3;
    int tok = tile*64 + r;
    uint4v v0, v1;
    if (tok < NTOK){
      const unsigned short* src = vp + (size_t)(b*NTOK + tok)*KDIM + head*64 + ch*16;
      v0 = *(const uint4v*)src;
      v1 = *(const uint4v*)(src + 8);
    } else { v0 = (uint4v)0; v1 = (uint4v)0; }
    *(uint4v*)&Tl[r][ch*16]     = v0;
    *(uint4v*)&Tl[r][ch*16 + 8] = v1;
  }
  __syncthreads();
  {
    int c = t & 63, rchunk = t >> 6;
    int tokBase = tile*64 + rchunk*16;
    if (tokBase < NKPAD){
      unsigned short ov[16];
      #pragma unroll
      for (int j=0;j<16;j++) ov[j] = Tl[rchunk*16 + j][c];
      unsigned short* dst = vt + ((size_t)(((b*16 + head) << 6) + c))*NKPAD + tokBase;
      *(uint4v*)dst       = *(const uint4v*)&ov[0];
      *(uint4v*)(dst + 8) = *(const uint4v*)&ov[8];
    }
  }
}

// ---------------- flash attention, swapped-operand + software-pipelined loads
// grid (B*H, ceil(N/64)); 4 independent waves, each owns 16 q rows.
__global__ __launch_bounds__(256) void attn_kernel(const unsigned short* __restrict__ qp,
    const unsigned short* __restrict__ kp, const unsigned short* __restrict__ vt,
    unsigned short* __restrict__ ctx)
{
  __shared__ alignas(16) unsigned short Plds[4][16][40];   // [wave][q=16][32 keys + 8 pad]
  int bh = blockIdx.x;
  int qt = blockIdx.y;
  int b = bh >> 4, h = bh & 15;
  int t = threadIdx.x, w = t >> 6, lane = t & 63;
  int g = lane >> 4, l15 = lane & 15;
  int qrow = qt*64 + w*16 + l15;
  int qcl = qrow > NTOK-1 ? NTOK-1 : qrow;
  const unsigned short* qb = qp + (((size_t)(b*NTOK + qcl)*NH + h) << 6);
  short8 qf[2];
  qf[0] = *(const short8*)(qb + g*8);
  qf[1] = *(const short8*)(qb + 32 + g*8);
  // K: A-operand rows = keys; lane loads key kt*32 + l15 (+16 for c1), e-chunk g*8 (+32)
  const unsigned short* kptr = kp + (((size_t)(b*NTOK + l15)*NH + h) << 6) + g*8;
  // V^T: A rows = d; lane row bh*64 + dblk*16 + l15, key col kt*32 + g*8
  const unsigned short* vptr = vt + ((size_t)((bh << 6) + l15))*NKPAD + g*8;
  unsigned short (*pl)[40] = Plds[w];
  float m_ = -3e38f, l_ = 0.f;
  f32x4 o_[4];
  #pragma unroll
  for (int d=0;d<4;d++) o_[d] = 0.f;

  // softmax + PV; V fragments passed in (already in flight before the barrier)
  auto soft_pv = [&](f32x4 c0, f32x4 c1, short8 va0, short8 va1, short8 va2, short8 va3){
    float mx = fmaxf(fmaxf(fmaxf(c0[0],c0[1]), fmaxf(c0[2],c0[3])),
                     fmaxf(fmaxf(c1[0],c1[1]), fmaxf(c1[2],c1[3])));
    mx = fmaxf(mx, __shfl_xor(mx, 16));
    mx = fmaxf(mx, __shfl_xor(mx, 32));
    float mn = fmaxf(m_, mx);
    float al = __expf(m_ - mn);
    m_ = mn;
    float p0[4], p1[4];
    float rs = 0.f;
    #pragma unroll
    for (int r=0;r<4;r++){
      p0[r] = __expf(c0[r] - mn);
      p1[r] = __expf(c1[r] - mn);
      rs += p0[r] + p1[r];
    }
    rs += __shfl_xor(rs, 16);
    rs += __shfl_xor(rs, 32);
    l_ = l_*al + rs;
    #pragma unroll
    for (int d=0;d<4;d++)
      #pragma unroll
      for (int r=0;r<4;r++) o_[d][r] *= al;
    // stage P: lane (g,l15) owns P[q=l15][keys g*4+0..3] and [16+g*4+0..3]
    uint2v w0, w1;
    w0[0] = pack_bf16(p0[0], p0[1]); w0[1] = pack_bf16(p0[2], p0[3]);
    w1[0] = pack_bf16(p1[0], p1[1]); w1[1] = pack_bf16(p1[2], p1[3]);
    *(uint2v*)&pl[l15][g*4]      = w0;
    *(uint2v*)&pl[l15][16 + g*4] = w1;
    asm volatile("s_waitcnt lgkmcnt(0)" ::: "memory");   // wave-local LDS ordering
    __builtin_amdgcn_sched_barrier(0);                   // rule #18: pin reads after waitcnt
    short8 pf = *(const short8*)&pl[l15][g*8];           // B-operand: P[q=l15][keys g*8..+8]
    o_[0] = mfma16(va0, pf, o_[0]);                      // D: row=d(g*4+r), col=q=l15
    o_[1] = mfma16(va1, pf, o_[1]);
    o_[2] = mfma16(va2, pf, o_[2]);
    o_[3] = mfma16(va3, pf, o_[3]);
  };

  // prologue: K(kt=0) in flight
  short8 ka0 = *(const short8*)(kptr);
  short8 ka1 = *(const short8*)(kptr + 32);
  short8 ka2 = *(const short8*)(kptr + 16*1024);
  short8 ka3 = *(const short8*)(kptr + 16*1024 + 32);
  kptr += 32*1024;

  for (int kt=0; kt<48; ++kt){
    // V loads for THIS tile, issued first (consumed after softmax, ~200+ cyc later)
    const unsigned short* vb = vptr + kt*32;
    short8 va0 = *(const short8*)(vb);
    short8 va1 = *(const short8*)(vb + (size_t)16*NKPAD);
    short8 va2 = *(const short8*)(vb + (size_t)32*NKPAD);
    short8 va3 = *(const short8*)(vb + (size_t)48*NKPAD);
    // QK^T with prefetched K
    f32x4 c0 = 0.f, c1 = 0.f;
    c0 = mfma16(ka0, qf[0], c0);
    c1 = mfma16(ka2, qf[0], c1);
    c0 = mfma16(ka1, qf[1], c0);
    c1 = mfma16(ka3, qf[1], c1);
    // prefetch K for kt+1 (kt=47 over-reads into RPAD padding — in-allocation, never consumed)
    ka0 = *(const short8*)(kptr);
    ka1 = *(const short8*)(kptr + 32);
    ka2 = *(const short8*)(kptr + 16*1024);
    ka3 = *(const short8*)(kptr + 16*1024 + 32);
    kptr += 32*1024;
    soft_pv(c0, c1, va0, va1, va2, va3);
  }
  // tail: keys 1536..1567, only 1536 valid
  {
    const unsigned short* vb = vptr + 48*32;
    short8 va0 = *(const short8*)(vb);
    short8 va1 = *(const short8*)(vb + (size_t)16*NKPAD);
    short8 va2 = *(const short8*)(vb + (size_t)32*NKPAD);
    short8 va3 = *(const short8*)(vb + (size_t)48*NKPAD);
    const unsigned short* k0 = kp + (((size_t)(b*NTOK + (NTOK-1))*NH + h) << 6) + g*8;
    short8 a00 = *(const short8*)(k0);
    short8 a01 = *(const short8*)(k0 + 32);
    f32x4 c0 = 0.f;
    c0 = mfma16(a00, qf[0], c0);
    c0 = mfma16(a01, qf[1], c0);
    f32x4 c1;
    #pragma unroll
    for (int r=0;r<4;r++){
      if (g*4 + r >= 1) c0[r] = -1e30f;
      c1[r] = -1e30f;
    }
    soft_pv(c0, c1, va0, va1, va2, va3);
  }
  // write: o_[dblk][r] = ctx[q=l15][d = dblk*16 + g*4 + r]
  int n = qt*64 + w*16 + l15;
  if (n < NTOK){
    float inv = 1.f / l_;
    unsigned short* cb = ctx + (((size_t)(b*NTOK + n)*NH + h) << 6) + g*4;
    #pragma unroll
    for (int d=0;d<4;d++){
      uint2v uu;
      uu[0] = pack_bf16(o_[d][0]*inv, o_[d][1]*inv);
      uu[1] = pack_bf16(o_[d][2]*inv, o_[d][3]*inv);
      *(uint2v*)(cb + d*16) = uu;
    }
  }
}

extern "C" void kernel_launch(void* const* d_in, const int* in_sizes, int n_in,
                              void* d_out, int out_size, void* d_ws, size_t ws_size,
                              hipStream_t stream)
{
  const float* x    = (const float*)d_in[0];
  const float* qkvw = (const float*)d_in[1];
  const float* ipw  = (const float*)d_in[2];
  const float* ipb  = (const float*)d_in[3];
  const float* opw  = (const float*)d_in[4];
  const float* opb  = (const float*)d_in[5];
  const float* pw   = (const float*)d_in[6];
  const float* pb   = (const float*)d_in[7];
  const int*   ids  = (const int*)d_in[8];
  float* out = (float*)d_out;

  char* p = (char*)d_ws;
  auto alloc = [&](size_t bytes)->char* {
    char* r = p; p += (bytes + 255) & ~(size_t)255; return r;
  };
  unsigned short* xb    = (unsigned short*)alloc((size_t)RPAD*1024*2);   // reused as vt
  unsigned short* qkvwb = (unsigned short*)alloc((size_t)3072*1024*2);
  unsigned short* ipwb  = (unsigned short*)alloc((size_t)3072*1024*2);
  unsigned short* opwb  = (unsigned short*)alloc((size_t)1024*1024*2);
  unsigned short* pwb   = (unsigned short*)alloc((size_t)1024*1024*2);
  unsigned short* qkvb  = (unsigned short*)alloc((size_t)RPAD*3072*2);
  unsigned short* qpb   = (unsigned short*)alloc((size_t)RPAD*1024*2);
  unsigned short* kpb   = (unsigned short*)alloc((size_t)RPAD*1024*2);
  unsigned short* vpb   = (unsigned short*)alloc((size_t)RPAD*1024*2);
  unsigned short* ctxb  = (unsigned short*)alloc((size_t)RPAD*1024*2);
  unsigned short* mhab  = (unsigned short*)alloc((size_t)RPAD*1024*2);
  int*   postab = (int*)alloc((size_t)B_*1536*4);
  float* ctab   = (float*)alloc(13*32*4);
  float* stab   = (float*)alloc(13*32*4);
  unsigned short* vtb = xb;   // alias: xb (12,845,056 B) == vt (4096*NKPAD*2)

  cvt_w_kernel<<<3072, 256, 0, stream>>>(qkvw, qkvwb, 3072*1024);
  cvt_w_kernel<<<3072, 256, 0, stream>>>(ipw,  ipwb,  3072*1024);
  cvt_w_kernel<<<1024, 256, 0, stream>>>(opw,  opwb,  1024*1024);
  cvt_w_kernel<<<1024, 256, 0, stream>>>(pw,   pwb,   1024*1024);
  cvt_x_kernel<<<RPAD, 256, 0, stream>>>(x, xb);
  rope_tables_kernel<<<1, 512, 0, stream>>>(ctab, stab);
  argsort_kernel<<<dim3(B_, 6), 256, 0, stream>>>(ids, postab);

  // qkv = x @ qkv_w^T  (no bias), bf16 out
  gemm_kernel<<<dim3(RPAD/128, 3072/128), 256, 0, stream>>>(xb, 1024, qkvwb, nullptr, 1.f,
                                                            qkvb, nullptr, 3072, NROWS);
  // RoPE in place on q,k
  rope_kernel<<<(B_*NTOK*NH + 255)/256, 256, 0, stream>>>(qkvb, postab, ctab, stab);
  // in_proj merged: qp (*0.125 folded), kp, vp
  gemm_inproj_kernel<<<dim3(RPAD/128, 8, 3), 256, 0, stream>>>(qkvb, ipwb, ipb, qpb, kpb, vpb);
  // V transpose into vt (aliases dead xb)
  vtrans_kernel<<<dim3(25, 16, 4), 256, 0, stream>>>(vpb, vtb);
  // attention
  attn_kernel<<<dim3(B_*NH, (NTOK+63)/64), 256, 0, stream>>>(qpb, kpb, vtb, ctxb);
  // out_proj then proj (final f32 to d_out)
  gemm_kernel<<<dim3(RPAD/128, 8), 256, 0, stream>>>(ctxb, 1024, opwb, opb, 1.f,
                                                     mhab, nullptr, 1024, NROWS);
  gemm_kernel<<<dim3(RPAD/128, 8), 256, 0, stream>>>(mhab, 1024, pwb,  pb,  1.f,
                                                     nullptr, out, 1024, NROWS);
}

// Round 6
// 456.987 us; speedup vs baseline: 1.2622x; 1.1996x over previous
//
#include <hip/hip_runtime.h>
#include <math.h>

#define B_ 4
#define NTOK 1537
#define NH 16
#define NROWS 6148      // B_*NTOK
#define RPAD 6272       // 49*128, padded rows
#define KDIM 1024
#define NKPAD 1568      // keys padded to 32-mult for aligned V^T loads

typedef __attribute__((ext_vector_type(8))) short short8;
typedef __attribute__((ext_vector_type(4))) float f32x4;
typedef __attribute__((ext_vector_type(16))) float f32x16;
typedef __attribute__((ext_vector_type(4))) unsigned short ushort4v;
typedef __attribute__((ext_vector_type(4))) unsigned int uint4v;
typedef __attribute__((ext_vector_type(2))) unsigned int uint2v;

__device__ __forceinline__ float bf2f(unsigned short u){
  unsigned int x = ((unsigned int)u) << 16;
  return __uint_as_float(x);
}
__device__ __forceinline__ unsigned short f2bf(float f){
  unsigned int x = __float_as_uint(f);
  x += 0x7fff + ((x >> 16) & 1);   // RNE
  return (unsigned short)(x >> 16);
}
__device__ __forceinline__ unsigned int pack_bf16(float lo, float hi){
  return (unsigned int)f2bf(lo) | ((unsigned int)f2bf(hi) << 16);
}
__device__ __forceinline__ void gload_lds16(const void* g, void* l){
  __builtin_amdgcn_global_load_lds((const __attribute__((address_space(1))) unsigned int*)g,
                                   (__attribute__((address_space(3))) unsigned int*)l, 16, 0, 0);
}
__device__ __forceinline__ f32x4 mfma16(short8 a, short8 b, f32x4 c){
  return __builtin_amdgcn_mfma_f32_16x16x32_bf16(a, b, c, 0, 0, 0);
}
__device__ __forceinline__ f32x16 mfma32(short8 a, short8 b, f32x16 c){
  return __builtin_amdgcn_mfma_f32_32x32x16_bf16(a, b, c, 0, 0, 0);
}

// ---------------- conversions ----------------
__global__ __launch_bounds__(256) void cvt_w_kernel(const float* __restrict__ src,
                                                    unsigned short* __restrict__ dst, int n){
  int i = (blockIdx.x*256 + threadIdx.x)*4;
  if (i >= n) return;
  f32x4 v = *(const f32x4*)(src + i);
  ushort4v o;
  #pragma unroll
  for (int j=0;j<4;j++) o[j] = f2bf(v[j]);
  *(ushort4v*)(dst + i) = o;
}

__global__ __launch_bounds__(256) void cvt_x_kernel(const float* __restrict__ x,
                                                    unsigned short* __restrict__ xb){
  size_t i = ((size_t)blockIdx.x*256 + threadIdx.x)*4;
  if (i >= (size_t)RPAD*KDIM) return;
  size_t row = i >> 10;
  ushort4v o;
  if (row < NROWS){
    f32x4 v = *(const f32x4*)(x + i);
    #pragma unroll
    for (int j=0;j<4;j++) o[j] = f2bf(v[j]);
  } else {
    o = (ushort4v)0;
  }
  *(ushort4v*)(xb + i) = o;
}

// ---------------- RoPE tables (pos 0..12, 32 freqs) ----------------
__global__ void rope_tables_kernel(float* __restrict__ ct, float* __restrict__ st){
  int i = threadIdx.x;
  if (i >= 13*32) return;
  int p = i >> 5, j = i & 31;
  float th = powf(10000.f, -(float)j * (1.f/32.f));
  float ang = (float)p * th;
  ct[i] = cosf(ang);
  st[i] = sinf(ang);
}

// ---------------- stable argsort -> pos table ----------------
// grid (B_, 6): each block ranks 256 elements of one batch.
__global__ __launch_bounds__(256) void argsort_kernel(const int* __restrict__ ids,
                                                      int* __restrict__ postab){
  __shared__ int vals[1536];
  int b = blockIdx.x;
  const int* src = ids + b*1536;
  for (int i=threadIdx.x; i<1536; i+=256) vals[i] = src[i];
  __syncthreads();
  int i = blockIdx.y*256 + threadIdx.x;
  int v = vals[i];
  int rank = 0;
  for (int j=0;j<1536;j++){
    int u = vals[j];
    rank += (u < v) || (u == v && j < i);   // stable rank
  }
  postab[b*1536 + rank] = (i % 12) + 1;     // (p % V) + 1
}

// ---------------- RoPE apply, in-place on bf16 qkv (q and k parts) ----------------
__global__ __launch_bounds__(256) void rope_kernel(unsigned short* __restrict__ qkv,
                                                   const int* __restrict__ postab,
                                                   const float* __restrict__ ct,
                                                   const float* __restrict__ st){
  int idx = blockIdx.x*256 + threadIdx.x;
  if (idx >= B_*NTOK*NH) return;
  int h = idx & 15;
  int bn = idx >> 4;
  int b = bn / NTOK;
  int n = bn - b*NTOK;
  unsigned short* rowp = qkv + (size_t)bn*3072;
  int pos = (n == 0) ? 0 : postab[b*1536 + (n-1)];
  const float* cr = ct + pos*32;
  const float* sr = st + pos*32;
  #pragma unroll
  for (int part=0; part<2; part++){
    unsigned short* p = rowp + part*1024 + h*64;
    uint4v vv[8];
    #pragma unroll
    for (int i=0;i<8;i++) vv[i] = ((const uint4v*)p)[i];
    unsigned short* tp = (unsigned short*)vv;
    unsigned short ov[64];
    if (n == 0){
      #pragma unroll
      for (int j=0;j<32;j++){ ov[j] = tp[2*j]; ov[32+j] = tp[2*j+1]; }
    } else {
      #pragma unroll
      for (int j=0;j<32;j++){
        float re = bf2f(tp[2*j]), im = bf2f(tp[2*j+1]);
        float c = cr[j], s = sr[j];
        ov[j]    = f2bf(re*c - im*s);
        ov[32+j] = f2bf(re*s + im*c);
      }
    }
    #pragma unroll
    for (int i=0;i<8;i++) ((uint4v*)p)[i] = ((const uint4v*)ov)[i];
  }
}

// ---------------- bf16 MFMA GEMM body: out[r][c] = (sum_k A[r][k]*W[c][k] + bias[c]) * scale
__device__ __forceinline__ void gemm_body(const unsigned short* __restrict__ A, int lda,
    const unsigned short* __restrict__ W,
    const float* __restrict__ bias, float scale,
    unsigned short* __restrict__ outb, float* __restrict__ outf, int ldo, int mvalid,
    int rowBase, int colBase)
{
  __shared__ alignas(16) unsigned short At[128][32];
  __shared__ alignas(16) unsigned short Bt[128][32];
  int t = threadIdx.x, w = t >> 6, lane = t & 63;
  int g = lane >> 4, l15 = lane & 15;
  int rb = (w >> 1) * 64, cb = (w & 1) * 64;
  f32x4 acc[4][4];
  #pragma unroll
  for (int m=0;m<4;m++)
    #pragma unroll
    for (int n=0;n<4;n++) acc[m][n] = 0.f;
  int srow = lane >> 2;            // 0..15
  int scol = (lane & 3) * 8;       // 0,8,16,24
  for (int kb = 0; kb < KDIM; kb += 32){
    __syncthreads();
    #pragma unroll
    for (int i=0;i<2;i++){
      int rr = i*64 + w*16 + srow;
      gload_lds16(A + (size_t)(rowBase + rr)*lda + kb + scol, &At[i*64 + w*16][0]);
      gload_lds16(W + (size_t)(colBase + rr)*KDIM + kb + scol, &Bt[i*64 + w*16][0]);
    }
    __syncthreads();
    short8 af[4], bf[4];
    #pragma unroll
    for (int m=0;m<4;m++) af[m] = *(const short8*)&At[rb + m*16 + l15][g*8];
    #pragma unroll
    for (int n=0;n<4;n++) bf[n] = *(const short8*)&Bt[cb + n*16 + l15][g*8];
    #pragma unroll
    for (int m=0;m<4;m++)
      #pragma unroll
      for (int n=0;n<4;n++)
        acc[m][n] = mfma16(af[m], bf[n], acc[m][n]);
  }
  #pragma unroll
  for (int m=0;m<4;m++)
    #pragma unroll
    for (int n=0;n<4;n++){
      int col = colBase + cb + n*16 + l15;
      float bv = bias ? bias[col] : 0.f;
      #pragma unroll
      for (int r=0;r<4;r++){
        int row = rowBase + rb + m*16 + g*4 + r;
        if (row < mvalid){
          float v = (acc[m][n][r] + bv) * scale;
          if (outf) outf[(size_t)row*ldo + col] = v;
          else      outb[(size_t)row*ldo + col] = f2bf(v);
        }
      }
    }
}

__global__ __launch_bounds__(256) void gemm_kernel(const unsigned short* __restrict__ A, int lda,
    const unsigned short* __restrict__ W,
    const float* __restrict__ bias, float scale,
    unsigned short* __restrict__ outb, float* __restrict__ outf, int ldo, int mvalid)
{
  gemm_body(A, lda, W, bias, scale, outb, outf, ldo, mvalid,
            blockIdx.x*128, blockIdx.y*128);
}

// merged in_proj: z = 0,1,2 -> q,k,v
__global__ __launch_bounds__(256) void gemm_inproj_kernel(const unsigned short* __restrict__ qkvb,
    const unsigned short* __restrict__ ipwb, const float* __restrict__ ipb,
    unsigned short* __restrict__ qpb, unsigned short* __restrict__ kpb,
    unsigned short* __restrict__ vpb)
{
  int z = blockIdx.z;
  const unsigned short* A = qkvb + z*1024;
  const unsigned short* W = ipwb + (size_t)z*1024*1024;
  const float* bias = ipb + z*1024;
  float scale = (z == 0) ? 0.125f : 1.f;
  unsigned short* outb = (z == 0) ? qpb : (z == 1 ? kpb : vpb);
  gemm_body(A, 3072, W, bias, scale, outb, nullptr, 1024, NROWS,
            blockIdx.x*128, blockIdx.y*128);
}

// ---------------- V transpose: vp[b*NTOK+n][h*64+e] -> vt[((b*16+h)*64+e)][NKPAD keys]
__global__ __launch_bounds__(256) void vtrans_kernel(const unsigned short* __restrict__ vp,
                                                     unsigned short* __restrict__ vt){
  __shared__ alignas(16) unsigned short Tl[64][72];
  int tile = blockIdx.x, head = blockIdx.y, b = blockIdx.z;
  int t = threadIdx.x;
  {
    int r = t >> 2, ch = t & 3;
    int tok = tile*64 + r;
    uint4v v0, v1;
    if (tok < NTOK){
      const unsigned short* src = vp + (size_t)(b*NTOK + tok)*KDIM + head*64 + ch*16;
      v0 = *(const uint4v*)src;
      v1 = *(const uint4v*)(src + 8);
    } else { v0 = (uint4v)0; v1 = (uint4v)0; }
    *(uint4v*)&Tl[r][ch*16]     = v0;
    *(uint4v*)&Tl[r][ch*16 + 8] = v1;
  }
  __syncthreads();
  {
    int c = t & 63, rchunk = t >> 6;
    int tokBase = tile*64 + rchunk*16;
    if (tokBase < NKPAD){
      unsigned short ov[16];
      #pragma unroll
      for (int j=0;j<16;j++) ov[j] = Tl[rchunk*16 + j][c];
      unsigned short* dst = vt + ((size_t)(((b*16 + head) << 6) + c))*NKPAD + tokBase;
      *(uint4v*)dst       = *(const uint4v*)&ov[0];
      *(uint4v*)(dst + 8) = *(const uint4v*)&ov[8];
    }
  }
}

// ---------------- flash attention, 32x32x16 MFMA, swapped operands, zero LDS
// grid (B*H, 13); 4 waves, each owns 32 q rows (block covers 128 q).
// Layouts (32x32x16): A row = l&31, k = (l>>5)*8+j ; B col = l&31, same k ;
// C/D col = l&31, row = (reg&3) + 8*(reg>>2) + 4*(l>>5)   [guide m74/m101]
__global__ __launch_bounds__(256) void attn_kernel(const unsigned short* __restrict__ qp,
    const unsigned short* __restrict__ kp, const unsigned short* __restrict__ vt,
    unsigned short* __restrict__ ctx)
{
  int bh = blockIdx.x;
  int qt = blockIdx.y;
  int b = bh >> 4, hd = bh & 15;
  int t = threadIdx.x, w = t >> 6, lane = t & 63;
  int l31 = lane & 31, hh = lane >> 5;
  int qrow = qt*128 + w*32 + l31;
  int qcl = qrow > NTOK-1 ? NTOK-1 : qrow;
  // Q B-frag: col=q=l31, k-chunk c at byte offset c*16 + hh*8 within the 64-elem head row
  const unsigned short* qb = qp + (((size_t)(b*NTOK + qcl)*NH + hd) << 6) + hh*8;
  short8 qf[4];
  #pragma unroll
  for (int c=0;c<4;c++) qf[c] = *(const short8*)(qb + c*16);
  // K A-frag: row=key=kt*32+l31, same k-offsets
  const unsigned short* kptr = kp + (((size_t)(b*NTOK + l31)*NH + hd) << 6) + hh*8;
  // V^T A-frag: row = d = dblk*32 + l31, col(key) = kt*32 + c*16 + hh*8
  const unsigned short* vptr = vt + ((size_t)(bh*64 + l31))*NKPAD + hh*8;
  float m_ = -3e38f, l_ = 0.f;
  f32x16 o0 = 0.f, o1 = 0.f;

  auto soft_pv = [&](f32x16 cc, short8 va00, short8 va01, short8 va10, short8 va11){
    // in-lane max tree over 16 vals + one cross-half reduce
    float t0 = fmaxf(fmaxf(cc[0],cc[1]), fmaxf(cc[2],cc[3]));
    float t1 = fmaxf(fmaxf(cc[4],cc[5]), fmaxf(cc[6],cc[7]));
    float t2 = fmaxf(fmaxf(cc[8],cc[9]), fmaxf(cc[10],cc[11]));
    float t3 = fmaxf(fmaxf(cc[12],cc[13]), fmaxf(cc[14],cc[15]));
    float mx = fmaxf(fmaxf(t0,t1), fmaxf(t2,t3));
    mx = fmaxf(mx, __shfl_xor(mx, 32));
    // defer-max (T13, THR=8): only rescale when max grows materially
    if (!__all(mx <= m_ + 8.f)){
      float mn = fmaxf(m_, mx);
      float al = __expf(m_ - mn);
      m_ = mn;
      l_ *= al;
      #pragma unroll
      for (int i=0;i<16;i++){ o0[i] *= al; o1[i] *= al; }
    }
    float p[16], rs = 0.f;
    #pragma unroll
    for (int i=0;i<16;i++){ p[i] = __expf(cc[i] - m_); }
    #pragma unroll
    for (int i=0;i<16;i++) rs += p[i];
    rs += __shfl_xor(rs, 32);
    l_ += rs;
    // pack: W[wd] = keys (reg 2wd, 2wd+1) for q=l31
    unsigned int W[8];
    #pragma unroll
    for (int wd=0; wd<8; wd++) W[wd] = pack_bf16(p[2*wd], p[2*wd+1]);
    // cross-half exchange: partner's complementary words (4 independent shfls)
    unsigned int Y0 = (unsigned int)__shfl_xor((int)(hh ? W[0] : W[2]), 32);
    unsigned int Y1 = (unsigned int)__shfl_xor((int)(hh ? W[1] : W[3]), 32);
    unsigned int Y2 = (unsigned int)__shfl_xor((int)(hh ? W[4] : W[6]), 32);
    unsigned int Y3 = (unsigned int)__shfl_xor((int)(hh ? W[5] : W[7]), 32);
    uint4v u0, u1;
    if (hh){ u0[0]=Y0; u0[1]=Y1; u0[2]=W[2]; u0[3]=W[3];
             u1[0]=Y2; u1[1]=Y3; u1[2]=W[6]; u1[3]=W[7]; }
    else   { u0[0]=W[0]; u0[1]=W[1]; u0[2]=Y0; u0[3]=Y1;
             u1[0]=W[4]; u1[1]=W[5]; u1[2]=Y2; u1[3]=Y3; }
    short8 pb0, pb1;
    __builtin_memcpy(&pb0, &u0, 16);
    __builtin_memcpy(&pb1, &u1, 16);
    o0 = mfma32(va00, pb0, o0);
    o0 = mfma32(va01, pb1, o0);
    o1 = mfma32(va10, pb0, o1);
    o1 = mfma32(va11, pb1, o1);
  };

  // prologue: K(kt=0) in flight
  short8 ka[4];
  #pragma unroll
  for (int c=0;c<4;c++) ka[c] = *(const short8*)(kptr + c*16);
  kptr += (size_t)32*NH*64;

  for (int kt=0; kt<48; ++kt){
    // V for this tile, issued first
    const unsigned short* vB = vptr + kt*32;
    short8 va00 = *(const short8*)(vB);
    short8 va01 = *(const short8*)(vB + 16);
    short8 va10 = *(const short8*)(vB + (size_t)32*NKPAD);
    short8 va11 = *(const short8*)(vB + (size_t)32*NKPAD + 16);
    // QK^T: 4 chained K-chunks
    f32x16 cc = 0.f;
    cc = mfma32(ka[0], qf[0], cc);
    cc = mfma32(ka[1], qf[1], cc);
    cc = mfma32(ka[2], qf[2], cc);
    cc = mfma32(ka[3], qf[3], cc);
    // prefetch K(kt+1); kt=47 over-reads rows <RPAD (in-allocation, never consumed)
    #pragma unroll
    for (int c=0;c<4;c++) ka[c] = *(const short8*)(kptr + c*16);
    kptr += (size_t)32*NH*64;
    soft_pv(cc, va00, va01, va10, va11);
  }
  // tail: keys 1536..1567; only key 1536 (reg 0, hh 0) valid
  {
    const unsigned short* vB = vptr + 48*32;
    short8 va00 = *(const short8*)(vB);
    short8 va01 = *(const short8*)(vB + 16);
    short8 va10 = *(const short8*)(vB + (size_t)32*NKPAD);
    short8 va11 = *(const short8*)(vB + (size_t)32*NKPAD + 16);
    const unsigned short* kb48 = kp + (((size_t)(b*NTOK + 1536)*NH + hd) << 6) + hh*8;
    short8 kt0[4];
    #pragma unroll
    for (int c=0;c<4;c++) kt0[c] = *(const short8*)(kb48 + c*16);
    f32x16 cc = 0.f;
    cc = mfma32(kt0[0], qf[0], cc);
    cc = mfma32(kt0[1], qf[1], cc);
    cc = mfma32(kt0[2], qf[2], cc);
    cc = mfma32(kt0[3], qf[3], cc);
    #pragma unroll
    for (int i=0;i<16;i++) cc[i] = (i == 0 && hh == 0) ? cc[i] : -1e30f;
    soft_pv(cc, va00, va01, va10, va11);
  }
  // write: o{0,1}[reg] -> ctx[q=l31][d = dblk*32 + 8*(reg>>2) + 4*hh + (reg&3)]
  if (qrow < NTOK){
    float inv = 1.f / l_;
    unsigned short* cb = ctx + (((size_t)(b*NTOK + qrow)*NH + hd) << 6) + 4*hh;
    #pragma unroll
    for (int s=0;s<4;s++){
      uint2v u;
      u[0] = pack_bf16(o0[4*s]*inv,   o0[4*s+1]*inv);
      u[1] = pack_bf16(o0[4*s+2]*inv, o0[4*s+3]*inv);
      *(uint2v*)(cb + 8*s) = u;
    }
    #pragma unroll
    for (int s=0;s<4;s++){
      uint2v u;
      u[0] = pack_bf16(o1[4*s]*inv,   o1[4*s+1]*inv);
      u[1] = pack_bf16(o1[4*s+2]*inv, o1[4*s+3]*inv);
      *(uint2v*)(cb + 32 + 8*s) = u;
    }
  }
}

extern "C" void kernel_launch(void* const* d_in, const int* in_sizes, int n_in,
                              void* d_out, int out_size, void* d_ws, size_t ws_size,
                              hipStream_t stream)
{
  const float* x    = (const float*)d_in[0];
  const float* qkvw = (const float*)d_in[1];
  const float* ipw  = (const float*)d_in[2];
  const float* ipb  = (const float*)d_in[3];
  const float* opw  = (const float*)d_in[4];
  const float* opb  = (const float*)d_in[5];
  const float* pw   = (const float*)d_in[6];
  const float* pb   = (const float*)d_in[7];
  const int*   ids  = (const int*)d_in[8];
  float* out = (float*)d_out;

  char* p = (char*)d_ws;
  auto alloc = [&](size_t bytes)->char* {
    char* r = p; p += (bytes + 255) & ~(size_t)255; return r;
  };
  unsigned short* xb    = (unsigned short*)alloc((size_t)RPAD*1024*2);   // reused as vt
  unsigned short* qkvwb = (unsigned short*)alloc((size_t)3072*1024*2);
  unsigned short* ipwb  = (unsigned short*)alloc((size_t)3072*1024*2);
  unsigned short* opwb  = (unsigned short*)alloc((size_t)1024*1024*2);
  unsigned short* pwb   = (unsigned short*)alloc((size_t)1024*1024*2);
  unsigned short* qkvb  = (unsigned short*)alloc((size_t)RPAD*3072*2);
  unsigned short* qpb   = (unsigned short*)alloc((size_t)RPAD*1024*2);
  unsigned short* kpb   = (unsigned short*)alloc((size_t)RPAD*1024*2);
  unsigned short* vpb   = (unsigned short*)alloc((size_t)RPAD*1024*2);
  unsigned short* ctxb  = (unsigned short*)alloc((size_t)RPAD*1024*2);
  unsigned short* mhab  = (unsigned short*)alloc((size_t)RPAD*1024*2);
  int*   postab = (int*)alloc((size_t)B_*1536*4);
  float* ctab   = (float*)alloc(13*32*4);
  float* stab   = (float*)alloc(13*32*4);
  unsigned short* vtb = xb;   // alias: xb (12,845,056 B) == vt (4096*NKPAD*2)

  cvt_w_kernel<<<3072, 256, 0, stream>>>(qkvw, qkvwb, 3072*1024);
  cvt_w_kernel<<<3072, 256, 0, stream>>>(ipw,  ipwb,  3072*1024);
  cvt_w_kernel<<<1024, 256, 0, stream>>>(opw,  opwb,  1024*1024);
  cvt_w_kernel<<<1024, 256, 0, stream>>>(pw,   pwb,   1024*1024);
  cvt_x_kernel<<<RPAD, 256, 0, stream>>>(x, xb);
  rope_tables_kernel<<<1, 512, 0, stream>>>(ctab, stab);
  argsort_kernel<<<dim3(B_, 6), 256, 0, stream>>>(ids, postab);

  // qkv = x @ qkv_w^T  (no bias), bf16 out
  gemm_kernel<<<dim3(RPAD/128, 3072/128), 256, 0, stream>>>(xb, 1024, qkvwb, nullptr, 1.f,
                                                            qkvb, nullptr, 3072, NROWS);
  // RoPE in place on q,k
  rope_kernel<<<(B_*NTOK*NH + 255)/256, 256, 0, stream>>>(qkvb, postab, ctab, stab);
  // in_proj merged: qp (*0.125 folded), kp, vp
  gemm_inproj_kernel<<<dim3(RPAD/128, 8, 3), 256, 0, stream>>>(qkvb, ipwb, ipb, qpb, kpb, vpb);
  // V transpose into vt (aliases dead xb)
  vtrans_kernel<<<dim3(25, 16, 4), 256, 0, stream>>>(vpb, vtb);
  // attention
  attn_kernel<<<dim3(B_*NH, 13), 256, 0, stream>>>(qpb, kpb, vtb, ctxb);
  // out_proj then proj (final f32 to d_out)
  gemm_kernel<<<dim3(RPAD/128, 8), 256, 0, stream>>>(ctxb, 1024, opwb, opb, 1.f,
                                                     mhab, nullptr, 1024, NROWS);
  gemm_kernel<<<dim3(RPAD/128, 8), 256, 0, stream>>>(mhab, 1024, pwb,  pb,  1.f,
                                                     nullptr, out, 1024, NROWS);
}